// Round 2
// baseline (917.310 us; speedup 1.0000x reference)
//
#include <hip/hip_runtime.h>
#include <stdint.h>

// ActorCritic fused kernels for MI355X (gfx950).
// Round 1 resubmit (R1 was a GPU-acquisition timeout; no data).
//   - actor & critic MLPs (2->256->256->{16,1}) fused per 64-row chunk
//   - W1 held as register-resident bf16 fragments (hi [+lo for critic])
//   - act1/act2 in XOR-swizzled LDS bf16 tiles
//   - mfma_f32_16x16x32_bf16 (A: m=l&15,k=8*(l>>4)+j ; C: col=l&15,row=4*(l>>4)+r)

typedef __attribute__((ext_vector_type(8))) short bf16x8;
typedef __attribute__((ext_vector_type(4))) float f32x4;

#define NROWS   800000
#define NCHUNK  12500      // NROWS / 64
#define OUT_ENT 800000
#define OUT_VP  800001     // 1024 floats (G=64 x S=16)
#define OUT_MASK 801025    // 800000 floats

__device__ __forceinline__ short f2bf(float x) {            // RNE float->bf16
  union { float f; uint32_t u; } v; v.f = x;
  return (short)(uint16_t)((v.u + 0x7FFFu + ((v.u >> 16) & 1u)) >> 16);
}
__device__ __forceinline__ float bf2f(short h) {
  union { uint32_t u; float f; } v; v.u = ((uint32_t)(uint16_t)h) << 16;
  return v.f;
}

__global__ void zero_kernel(float* out, float* wsf) {
  int t = threadIdx.x + blockIdx.x * blockDim.x;
  for (int i = t; i < 1025; i += 1024) out[OUT_ENT + i] = 0.0f;
  if (t == 0) { wsf[0] = 0.0f; wsf[1] = 0.0f; }
}

__global__ void final_kernel(float* out, const float* wsf) {
  if (threadIdx.x == 0 && blockIdx.x == 0)
    out[OUT_ENT] = (wsf[1] > 0.0f) ? (wsf[0] / wsf[1]) : 0.0f;
}

// Dynamic-LDS layout (bytes). All offsets 16B-aligned.
#define L_ACT1 0          // [64][256] bf16, swizzled   (32768)
#define L_ACT2 32768      // [64][256] bf16, swizzled   (32768)
#define L_W2H  65536      // [16][256] bf16, swizzled   (8192)
#define L_W2L  73728      // [16][256] bf16, swizzled   (8192)
#define L_W0   81920      // [2][256] f32               (2048)
#define L_B0   83968      // [256] f32                  (1024)
#define L_H    84992      // [64][2] f32                (512)
#define L_MF   85504      // [64] f32                   (256)
#define L_ALP  85760      // [64] f32                   (256)
#define LDS_SZ 86016

// ROLE: 0 = actor, 1 = critic
template <int ROLE>
__global__ void __launch_bounds__(512) ac_main(
    const float* __restrict__ ob, const int* __restrict__ action,
    const int* __restrict__ graph_ids,
    const float* __restrict__ aW0, const float* __restrict__ ab0,
    const float* __restrict__ aW1, const float* __restrict__ ab1,
    const float* __restrict__ aW2, const float* __restrict__ ab2,
    const float* __restrict__ cW0, const float* __restrict__ cb0,
    const float* __restrict__ cW1, const float* __restrict__ cb1,
    const float* __restrict__ cW2, const float* __restrict__ cb2,
    float* __restrict__ out, float* __restrict__ wsf)
{
  extern __shared__ char smem[];
  float* w0buf = (float*)(smem + L_W0);
  float* b0buf = (float*)(smem + L_B0);
  float* hbuf  = (float*)(smem + L_H);
  float* mfbuf = (float*)(smem + L_MF);
  float* albuf = (float*)(smem + L_ALP);
  __shared__ float went[8], wmf[8];

  const int tid  = threadIdx.x;
  const int lane = tid & 63;
  const int wave = tid >> 6;
  const int l15  = lane & 15;
  const int l4   = lane >> 4;

  const float* W0 = ROLE ? cW0 : aW0;
  const float* B0 = ROLE ? cb0 : ab0;
  const float* W1 = ROLE ? cW1 : aW1;
  const float* B1 = ROLE ? cb1 : ab1;

  // --- per-block one-time setup -------------------------------------------
  w0buf[tid & 511] = W0[tid & 511];                 // 512 threads -> all 512
  if (tid < 256) b0buf[tid] = B0[tid];

  // W2 (padded to 16 cols for critic) -> swizzled LDS, hi/lo bf16
  for (int id = tid; id < 4096; id += 512) {
    int n = id >> 8, k = id & 255;
    float w = ROLE ? ((n == 0) ? cW2[k] : 0.0f) : aW2[k * 16 + n];
    short hi = f2bf(w);
    short lo = f2bf(w - bf2f(hi));
    int byteoff = n * 512 + ((k * 2) ^ ((n & 7) << 4));
    *(short*)(smem + L_W2H + byteoff) = hi;
    *(short*)(smem + L_W2L + byteoff) = lo;
  }

  const int colbase = wave * 32;                    // each wave owns 32 N-cols
  float b1lane[2] = { B1[colbase + l15], B1[colbase + 16 + l15] };
  float b2lane = ROLE ? cb2[0] : ab2[l15];

  // W1 fragments, register resident.  B[k][n]: n = l15 (per ct), k = ks*32+8*l4+j
  bf16x8 bh[2][8], bl[2][8];
  #pragma unroll
  for (int ct = 0; ct < 2; ++ct) {
    const int n = colbase + ct * 16 + l15;
    #pragma unroll
    for (int ks = 0; ks < 8; ++ks) {
      const int k0 = ks * 32 + 8 * l4;
      bf16x8 h8, l8;
      #pragma unroll
      for (int j = 0; j < 8; ++j) {
        float w = W1[(k0 + j) * 256 + n];
        short hi = f2bf(w);
        h8[j] = hi;
        l8[j] = f2bf(w - bf2f(hi));
      }
      bh[ct][ks] = h8;
      if (ROLE) bl[ct][ks] = l8;                    // critic only uses lo
    }
  }
  __syncthreads();

  float entacc = 0.0f, mfacc = 0.0f;

  // --- chunk loop: 64 rows (= 4 edges) per chunk --------------------------
  for (int c = (int)blockIdx.x; c < NCHUNK; c += (int)gridDim.x) {
    const int row0 = c * 64;

    // Phase 1: h, mask
    if (tid < 64) {
      float o0 = ob[(row0 + tid) * 3 + 0];
      float h0 = ob[(row0 + tid) * 3 + 1];
      float h1 = ob[(row0 + tid) * 3 + 2];
      float mf = ((int)o0 == 0) ? 1.0f : 0.0f;
      hbuf[tid * 2 + 0] = h0;
      hbuf[tid * 2 + 1] = h1;
      mfbuf[tid] = mf;
      if (!ROLE) out[OUT_MASK + row0 + tid] = mf;   // edge_mask output
    }
    __syncthreads();

    // Phase 2: act1 = relu(h @ W0 + b0) -> swizzled bf16 LDS
    #pragma unroll
    for (int i = 0; i < 4; ++i) {
      int task = tid + 512 * i;                     // 2048 tasks = 64 rows x 32 kblocks
      int row = task >> 5, kb = task & 31;
      float h0 = hbuf[row * 2 + 0], h1 = hbuf[row * 2 + 1];
      bf16x8 v;
      #pragma unroll
      for (int j = 0; j < 8; ++j) {
        int colj = kb * 8 + j;
        float a = fmaf(h0, w0buf[colj], fmaf(h1, w0buf[256 + colj], b0buf[colj]));
        v[j] = f2bf(fmaxf(a, 0.0f));
      }
      *(bf16x8*)(smem + L_ACT1 + row * 512 + ((kb * 16) ^ ((row & 7) << 4))) = v;
    }
    __syncthreads();

    // Phase 3: GEMM1 (256x256), row-tile pairs for 4 independent MFMA chains
    #pragma unroll 1
    for (int rtp = 0; rtp < 2; ++rtp) {
      bf16x8 af[2][8];
      #pragma unroll
      for (int h = 0; h < 2; ++h) {
        int row = (rtp * 2 + h) * 16 + l15;
        #pragma unroll
        for (int ks = 0; ks < 8; ++ks)
          af[h][ks] = *(const bf16x8*)(smem + L_ACT1 + row * 512 +
                                       ((ks * 64 + 16 * l4) ^ ((row & 7) << 4)));
      }
      f32x4 acc[2][2];
      #pragma unroll
      for (int h = 0; h < 2; ++h)
        #pragma unroll
        for (int ct = 0; ct < 2; ++ct) acc[h][ct] = (f32x4){0.f, 0.f, 0.f, 0.f};

      #pragma unroll
      for (int ks = 0; ks < 8; ++ks) {
        #pragma unroll
        for (int h = 0; h < 2; ++h)
          #pragma unroll
          for (int ct = 0; ct < 2; ++ct)
            acc[h][ct] = __builtin_amdgcn_mfma_f32_16x16x32_bf16(af[h][ks], bh[ct][ks], acc[h][ct], 0, 0, 0);
        if (ROLE) {
          #pragma unroll
          for (int h = 0; h < 2; ++h)
            #pragma unroll
            for (int ct = 0; ct < 2; ++ct)
              acc[h][ct] = __builtin_amdgcn_mfma_f32_16x16x32_bf16(af[h][ks], bl[ct][ks], acc[h][ct], 0, 0, 0);
        }
      }
      // epilogue: +bias, relu -> swizzled bf16 act2
      #pragma unroll
      for (int h = 0; h < 2; ++h) {
        #pragma unroll
        for (int ct = 0; ct < 2; ++ct) {
          int col = colbase + ct * 16 + l15;
          #pragma unroll
          for (int r = 0; r < 4; ++r) {
            int row = (rtp * 2 + h) * 16 + 4 * l4 + r;
            float vv = fmaxf(acc[h][ct][r] + b1lane[ct], 0.0f);
            *(short*)(smem + L_ACT2 + row * 512 + ((col * 2) ^ ((row & 7) << 4))) = f2bf(vv);
          }
        }
      }
    }
    __syncthreads();

    // Phase 4: head GEMM (256 -> 16) + epilogue; waves 0..3, one row-tile (= edge) each
    if (wave < 4) {
      const int rt = wave;
      f32x4 acc_e = {0.f, 0.f, 0.f, 0.f}, acc_o = {0.f, 0.f, 0.f, 0.f};
      #pragma unroll
      for (int ks = 0; ks < 8; ks += 2) {
        int row = rt * 16 + l15;
        bf16x8 a0 = *(const bf16x8*)(smem + L_ACT2 + row * 512 + ((ks * 64 + 16 * l4) ^ ((row & 7) << 4)));
        bf16x8 a1 = *(const bf16x8*)(smem + L_ACT2 + row * 512 + (((ks + 1) * 64 + 16 * l4) ^ ((row & 7) << 4)));
        int wb0 = l15 * 512 + ((ks * 64 + 16 * l4) ^ ((l15 & 7) << 4));
        int wb1 = l15 * 512 + (((ks + 1) * 64 + 16 * l4) ^ ((l15 & 7) << 4));
        acc_e = __builtin_amdgcn_mfma_f32_16x16x32_bf16(a0, *(const bf16x8*)(smem + L_W2H + wb0), acc_e, 0, 0, 0);
        acc_o = __builtin_amdgcn_mfma_f32_16x16x32_bf16(a1, *(const bf16x8*)(smem + L_W2H + wb1), acc_o, 0, 0, 0);
        if (ROLE) {
          acc_e = __builtin_amdgcn_mfma_f32_16x16x32_bf16(a0, *(const bf16x8*)(smem + L_W2L + wb0), acc_e, 0, 0, 0);
          acc_o = __builtin_amdgcn_mfma_f32_16x16x32_bf16(a1, *(const bf16x8*)(smem + L_W2L + wb1), acc_o, 0, 0, 0);
        }
      }
      f32x4 acc;
      #pragma unroll
      for (int r = 0; r < 4; ++r) acc[r] = acc_e[r] + acc_o[r];

      if (!ROLE) {
        // actor: log-softmax over the 16 classes (class = l15)
        #pragma unroll
        for (int r = 0; r < 4; ++r) {
          int rl = rt * 16 + 4 * l4 + r;
          float x = acc[r] + b2lane;
          float m = x;
          #pragma unroll
          for (int d = 1; d < 16; d <<= 1) m = fmaxf(m, __shfl_xor(m, d));
          float p = __expf(x - m);
          float s = p, t = p * (x - m);
          #pragma unroll
          for (int d = 1; d < 16; d <<= 1) { s += __shfl_xor(s, d); t += __shfl_xor(t, d); }
          float ls = __logf(s);
          float mfr = mfbuf[rl];
          int av = action[row0 + rl];
          if (l15 == av) albuf[rl] = (x - (m + ls)) * mfr;
          if (l15 == 0) { entacc += (ls - t / s) * mfr; mfacc += mfr; }
        }
      } else {
        // critic: masked value -> segment sum (edge e = c*4 + rt, all 16 s slots)
        int g = graph_ids[c * 4 + rt];
        if (l15 == 0) {
          #pragma unroll
          for (int r = 0; r < 4; ++r) {
            int sidx = 4 * l4 + r;
            float mfr = mfbuf[rt * 16 + sidx];
            if (mfr != 0.0f)
              atomicAdd(&out[OUT_VP + g * 16 + sidx], (acc[r] + b2lane) * (1.0f / 50000.0f));
          }
        }
      }
    }
    __syncthreads();
    if (!ROLE && tid < 64) out[row0 + tid] = albuf[tid];   // coalesced alp write
  }

  // entropy num/den block reduction -> global atomics (actor only)
  if (!ROLE) {
    #pragma unroll
    for (int d = 1; d < 64; d <<= 1) { entacc += __shfl_xor(entacc, d); mfacc += __shfl_xor(mfacc, d); }
    if (lane == 0) { went[wave] = entacc; wmf[wave] = mfacc; }
  }
  __syncthreads();
  if (!ROLE && tid == 0) {
    float e = 0.f, m = 0.f;
    #pragma unroll
    for (int i = 0; i < 8; ++i) { e += went[i]; m += wmf[i]; }
    atomicAdd(&wsf[0], e);
    atomicAdd(&wsf[1], m);
  }
}

extern "C" void kernel_launch(void* const* d_in, const int* in_sizes, int n_in,
                              void* d_out, int out_size, void* d_ws, size_t ws_size,
                              hipStream_t stream) {
  const float* ob     = (const float*)d_in[0];
  const int*   action = (const int*)d_in[1];
  const int*   gids   = (const int*)d_in[2];
  const float* aW0 = (const float*)d_in[3],  *ab0 = (const float*)d_in[4];
  const float* aW1 = (const float*)d_in[5],  *ab1 = (const float*)d_in[6];
  const float* aW2 = (const float*)d_in[7],  *ab2 = (const float*)d_in[8];
  const float* cW0 = (const float*)d_in[9],  *cb0 = (const float*)d_in[10];
  const float* cW1 = (const float*)d_in[11], *cb1 = (const float*)d_in[12];
  const float* cW2 = (const float*)d_in[13], *cb2 = (const float*)d_in[14];
  float* out = (float*)d_out;
  float* wsf = (float*)d_ws;

  zero_kernel<<<2, 512, 0, stream>>>(out, wsf);
  ac_main<0><<<256, 512, LDS_SZ, stream>>>(ob, action, gids, aW0, ab0, aW1, ab1, aW2, ab2,
                                           cW0, cb0, cW1, cb1, cW2, cb2, out, wsf);
  ac_main<1><<<256, 512, LDS_SZ, stream>>>(ob, action, gids, aW0, ab0, aW1, ab1, aW2, ab2,
                                           cW0, cb0, cW1, cb1, cW2, cb2, out, wsf);
  final_kernel<<<1, 64, 0, stream>>>(out, wsf);
}

// Round 3
// 584.032 us; speedup vs baseline: 1.5706x; 1.5706x over previous
//
#include <hip/hip_runtime.h>
#include <stdint.h>

// ActorCritic fused kernels for MI355X (gfx950). Round 3.
//   R2 post-mortem: latency/LDS-pipe bound (Occ 21.6% = 1 block/CU cap, 8.5e7 bank
//   conflicts from scalar stride-8 W0 reads, critic spilling at VGPR=128).
//   R3: actor 2 blocks/CU (78KB LDS, VGPR<=128); critic VGPR<=256 (no spill);
//       float4 W0 reads; DPP reductions (off the DS pipe); packed b32 act2 stores;
//       ob/action/gid prefetch pipeline; 3 barriers/chunk; critic head = VALU dot.

typedef __attribute__((ext_vector_type(8))) short bf16x8;
typedef __attribute__((ext_vector_type(4))) float f32x4;

#define NROWS    800000
#define NCHUNK   12500      // NROWS / 64
#define OUT_ENT  800000
#define OUT_VP   800001     // 1024 floats (G=64 x S=16)
#define OUT_MASK 801025     // 800000 floats

__device__ __forceinline__ short f2bf(float x) {            // RNE float->bf16
  union { float f; uint32_t u; } v; v.f = x;
  return (short)(uint16_t)((v.u + 0x7FFFu + ((v.u >> 16) & 1u)) >> 16);
}
__device__ __forceinline__ float bf2f(short h) {
  union { uint32_t u; float f; } v; v.u = ((uint32_t)(uint16_t)h) << 16;
  return v.f;
}
// DPP helpers (VALU pipe, not DS). quad_perm(1,0,3,2)=0xB1, quad_perm(2,3,0,1)=0x4E,
// ROW_ROR:4=0x124, ROW_ROR:8=0x128, ROW_HALF_MIRROR=0x141.
template <int C>
__device__ __forceinline__ float dppf(float x) {
  int r = __builtin_amdgcn_update_dpp(0, __builtin_bit_cast(int, x), C, 0xF, 0xF, true);
  return __builtin_bit_cast(float, r);
}
__device__ __forceinline__ float red16_sum(float x) {
  x += dppf<0xB1>(x); x += dppf<0x4E>(x); x += dppf<0x124>(x); x += dppf<0x128>(x); return x;
}
__device__ __forceinline__ float red16_max(float x) {
  x = fmaxf(x, dppf<0xB1>(x)); x = fmaxf(x, dppf<0x4E>(x));
  x = fmaxf(x, dppf<0x124>(x)); x = fmaxf(x, dppf<0x128>(x)); return x;
}
__device__ __forceinline__ float red8_sum(float x) {
  x += dppf<0xB1>(x); x += dppf<0x4E>(x); x += dppf<0x141>(x); return x;
}
__device__ __forceinline__ uint32_t cvt_pk_bf16(float a, float b) {   // lo=bf16(a), hi=bf16(b)
  uint32_t r; asm("v_cvt_pk_bf16_f32 %0, %1, %2" : "=v"(r) : "v"(a), "v"(b)); return r;
}

__global__ void zero_kernel(float* out, float* wsf) {
  int t = threadIdx.x + blockIdx.x * blockDim.x;
  for (int i = t; i < 1025; i += 1024) out[OUT_ENT + i] = 0.0f;
  if (t == 0) { wsf[0] = 0.0f; wsf[1] = 0.0f; }
}
__global__ void final_kernel(float* out, const float* wsf) {
  if (threadIdx.x == 0 && blockIdx.x == 0)
    out[OUT_ENT] = (wsf[1] > 0.0f) ? (wsf[0] / wsf[1]) : 0.0f;
}

// ---------------- actor LDS layout (78336 B <= 80KB -> 2 blocks/CU) ----------------
#define A_ACT1 0          // [64][256] bf16 swizzled (32768)
#define A_ACT2 32768      // [64][256] bf16 swizzled (32768)
#define A_W2H  65536      // [16][256] bf16 swizzled (8192)
#define A_W0   73728      // [2][256] f32 (2048)
#define A_B0   75776      // [256] f32 (1024)
#define A_OB   76800      // [192(+pad)] f32 (1024)
#define A_AB   77824      // [64] int (256)
#define A_MF   78080      // [64] f32 (256)
#define A_SZ   78336

__global__ void __launch_bounds__(512, 4) ac_actor(
    const float* __restrict__ ob, const int* __restrict__ action,
    const float* __restrict__ aW0, const float* __restrict__ ab0,
    const float* __restrict__ aW1, const float* __restrict__ ab1,
    const float* __restrict__ aW2, const float* __restrict__ ab2,
    float* __restrict__ out, float* __restrict__ wsf)
{
  extern __shared__ char smem[];
  float* w0buf = (float*)(smem + A_W0);
  float* b0buf = (float*)(smem + A_B0);
  float* obuf  = (float*)(smem + A_OB);
  int*   abuf  = (int*)(smem + A_AB);
  float* mfbuf = (float*)(smem + A_MF);
  const f32x4* w04 = (const f32x4*)(smem + A_W0);
  const f32x4* b04 = (const f32x4*)(smem + A_B0);
  __shared__ float went[8], wmf[8];

  const int tid = threadIdx.x, lane = tid & 63, wave = tid >> 6;
  const int l15 = lane & 15, l4 = lane >> 4;
  const int swzA = (l15 & 7) << 4;

  // setup
  w0buf[tid] = aW0[tid];
  if (tid < 256) b0buf[tid] = ab0[tid];
  for (int id = tid; id < 4096; id += 512) {      // W2 hi -> swizzled LDS
    int n = id >> 8, k = id & 255;
    *(short*)(smem + A_W2H + n * 512 + ((k * 2) ^ ((n & 7) << 4))) = f2bf(aW2[k * 16 + n]);
  }
  const int colbase = wave * 32;
  float b1lane[2] = { ab1[colbase + l15], ab1[colbase + 16 + l15] };
  float b2lane = ab2[l15];
  bf16x8 bh[2][8];                                // W1 hi fragments, register-resident
  #pragma unroll
  for (int ct = 0; ct < 2; ++ct) {
    const int n = colbase + ct * 16 + l15;
    #pragma unroll
    for (int ks = 0; ks < 8; ++ks) {
      const int k0 = ks * 32 + 8 * l4;
      bf16x8 h8;
      #pragma unroll
      for (int j = 0; j < 8; ++j) h8[j] = f2bf(aW1[(k0 + j) * 256 + n]);
      bh[ct][ks] = h8;
    }
  }
  // prologue stage (chunk c0)
  const int c0 = blockIdx.x, stride = gridDim.x;
  float sob = 0.0f; int sac = 0;
  if (tid < 192) sob = ob[c0 * 192 + tid];
  if (tid < 64)  sac = action[c0 * 64 + tid];
  __syncthreads();

  float entacc = 0.0f, mfacc = 0.0f;
  for (int c = c0; c < NCHUNK; c += stride) {
    const int row0 = c * 64;
    // --- A: land staged ob ---
    if (tid < 192) obuf[tid] = sob;
    __syncthreads();                              // B1
    // --- P2: mask + act1; issue next-chunk stage ---
    if (tid < 64) {
      float mf = ((int)obuf[tid * 3] == 0) ? 1.0f : 0.0f;
      mfbuf[tid] = mf;
      out[OUT_MASK + row0 + tid] = mf;
      abuf[tid] = sac;
    }
    int cn = c + stride;
    if (cn < NCHUNK) {
      if (tid < 192) sob = ob[cn * 192 + tid];
      if (tid < 64)  sac = action[cn * 64 + tid];
    }
    {
      const int kb = tid & 31;
      f32x4 wa0 = w04[kb * 2], wa1 = w04[kb * 2 + 1];
      f32x4 wb0 = w04[64 + kb * 2], wb1 = w04[64 + kb * 2 + 1];
      f32x4 ba0 = b04[kb * 2], ba1 = b04[kb * 2 + 1];
      #pragma unroll
      for (int i = 0; i < 4; ++i) {
        int row = wave * 2 + 16 * i + (lane >> 5);
        float h0 = obuf[row * 3 + 1], h1 = obuf[row * 3 + 2];
        bf16x8 v;
        #pragma unroll
        for (int j = 0; j < 4; ++j) {
          v[j]     = f2bf(fmaxf(fmaf(h0, wa0[j], fmaf(h1, wb0[j], ba0[j])), 0.0f));
          v[4 + j] = f2bf(fmaxf(fmaf(h0, wa1[j], fmaf(h1, wb1[j], ba1[j])), 0.0f));
        }
        *(bf16x8*)(smem + A_ACT1 + row * 512 + ((kb * 16) ^ ((row & 7) << 4))) = v;
      }
    }
    __syncthreads();                              // B2: act1 ready
    // --- P3: GEMM1 ---
    const bool evn = (l15 & 1) == 0;
    #pragma unroll 1
    for (int rtp = 0; rtp < 2; ++rtp) {
      f32x4 acc[2][2];
      #pragma unroll
      for (int h = 0; h < 2; ++h)
        #pragma unroll
        for (int ct = 0; ct < 2; ++ct) acc[h][ct] = (f32x4){0.f, 0.f, 0.f, 0.f};
      const int rA0 = rtp * 32 + l15, rA1 = rA0 + 16;
      #pragma unroll
      for (int ks = 0; ks < 8; ++ks) {
        const int cb = (ks * 64 + 16 * l4) ^ swzA;
        bf16x8 a0 = *(const bf16x8*)(smem + A_ACT1 + rA0 * 512 + cb);
        bf16x8 a1 = *(const bf16x8*)(smem + A_ACT1 + rA1 * 512 + cb);
        acc[0][0] = __builtin_amdgcn_mfma_f32_16x16x32_bf16(a0, bh[0][ks], acc[0][0], 0, 0, 0);
        acc[0][1] = __builtin_amdgcn_mfma_f32_16x16x32_bf16(a0, bh[1][ks], acc[0][1], 0, 0, 0);
        acc[1][0] = __builtin_amdgcn_mfma_f32_16x16x32_bf16(a1, bh[0][ks], acc[1][0], 0, 0, 0);
        acc[1][1] = __builtin_amdgcn_mfma_f32_16x16x32_bf16(a1, bh[1][ks], acc[1][1], 0, 0, 0);
      }
      #pragma unroll
      for (int ct = 0; ct < 2; ++ct) {
        const int colb = (colbase + ct * 16 + (l15 & ~1)) * 2;
        #pragma unroll
        for (int r = 0; r < 4; ++r) {
          float v0 = fmaxf(acc[0][ct][r] + b1lane[ct], 0.0f);
          float v1 = fmaxf(acc[1][ct][r] + b1lane[ct], 0.0f);
          float n0 = dppf<0xB1>(v0), n1 = dppf<0xB1>(v1);
          uint32_t w = cvt_pk_bf16(evn ? v0 : n1, evn ? n0 : v1);
          int rr = rtp * 32 + (evn ? 0 : 16) + 4 * l4 + r;
          int swzE = ((4 * l4 + r) & 7) << 4;
          *(uint32_t*)(smem + A_ACT2 + rr * 512 + (colb ^ swzE)) = w;
        }
      }
    }
    __syncthreads();                              // B3: act2 ready
    // --- P4: head GEMM + log-softmax (waves 0-3) ---
    if (wave < 4) {
      const int rowA = wave * 16 + l15;
      f32x4 ae = {0.f,0.f,0.f,0.f}, ao = {0.f,0.f,0.f,0.f};
      #pragma unroll
      for (int ks = 0; ks < 8; ks += 2) {
        const int cb0 = (ks * 64 + 16 * l4) ^ swzA;
        const int cb1 = ((ks + 1) * 64 + 16 * l4) ^ swzA;
        bf16x8 a0 = *(const bf16x8*)(smem + A_ACT2 + rowA * 512 + cb0);
        bf16x8 a1 = *(const bf16x8*)(smem + A_ACT2 + rowA * 512 + cb1);
        bf16x8 w0f = *(const bf16x8*)(smem + A_W2H + l15 * 512 + cb0);
        bf16x8 w1f = *(const bf16x8*)(smem + A_W2H + l15 * 512 + cb1);
        ae = __builtin_amdgcn_mfma_f32_16x16x32_bf16(a0, w0f, ae, 0, 0, 0);
        ao = __builtin_amdgcn_mfma_f32_16x16x32_bf16(a1, w1f, ao, 0, 0, 0);
      }
      #pragma unroll
      for (int r = 0; r < 4; ++r) {
        const int rl = wave * 16 + 4 * l4 + r;
        float x = ae[r] + ao[r] + b2lane;
        float m = red16_max(x);
        float e = __expf(x - m);
        float s = red16_sum(e);
        float t = red16_sum(e * (x - m));
        float ls = __logf(s);
        float mfr = mfbuf[rl];
        int av = abuf[rl];
        if (l15 == av) out[row0 + rl] = (x - m - ls) * mfr;
        if (l15 == 0) { entacc += (ls - t / s) * mfr; mfacc += mfr; }
      }
    }
    // no barrier needed: next A writes obuf only (not read in P4); B1 fences the rest
  }
  // entropy num/den -> global atomics
  #pragma unroll
  for (int d = 1; d < 64; d <<= 1) { entacc += __shfl_xor(entacc, d); mfacc += __shfl_xor(mfacc, d); }
  if (lane == 0) { went[wave] = entacc; wmf[wave] = mfacc; }
  __syncthreads();
  if (tid == 0) {
    float e = 0.f, m = 0.f;
    #pragma unroll
    for (int i = 0; i < 8; ++i) { e += went[i]; m += wmf[i]; }
    atomicAdd(&wsf[0], e); atomicAdd(&wsf[1], m);
  }
}

// ---------------- critic LDS layout (70976 B, 1 block/CU, VGPR<=256) ----------------
#define C_ACT1 0
#define C_ACT2 32768
#define C_W0   65536      // 2048
#define C_B0   67584      // 1024
#define C_W2F  68608      // [256] f32 (1024)
#define C_OB   69632      // 1024
#define C_GB   70656      // [4] int (64)
#define C_MF   70720      // 256
#define C_SZ   70976

__global__ void __launch_bounds__(512, 2) ac_critic(
    const float* __restrict__ ob, const int* __restrict__ graph_ids,
    const float* __restrict__ cW0, const float* __restrict__ cb0,
    const float* __restrict__ cW1, const float* __restrict__ cb1,
    const float* __restrict__ cW2, const float* __restrict__ cb2,
    float* __restrict__ out)
{
  extern __shared__ char smem[];
  float* w0buf = (float*)(smem + C_W0);
  float* b0buf = (float*)(smem + C_B0);
  float* w2buf = (float*)(smem + C_W2F);
  float* obuf  = (float*)(smem + C_OB);
  int*   gbuf  = (int*)(smem + C_GB);
  float* mfbuf = (float*)(smem + C_MF);
  const f32x4* w04 = (const f32x4*)(smem + C_W0);
  const f32x4* b04 = (const f32x4*)(smem + C_B0);
  const f32x4* w24 = (const f32x4*)(smem + C_W2F);

  const int tid = threadIdx.x, lane = tid & 63, wave = tid >> 6;
  const int l15 = lane & 15, l4 = lane >> 4;
  const int swzA = (l15 & 7) << 4;

  w0buf[tid] = cW0[tid];
  if (tid < 256) b0buf[tid] = cb0[tid];
  if (tid >= 256 && tid < 512) w2buf[tid - 256] = cW2[tid - 256];
  const float cb2v = cb2[0];
  const int colbase = wave * 32;
  float b1lane[2] = { cb1[colbase + l15], cb1[colbase + 16 + l15] };

  bf16x8 bh[2][8], bl[2][8];                      // W1 hi+lo fragments (no spill at 256 VGPR)
  #pragma unroll
  for (int ct = 0; ct < 2; ++ct) {
    const int n = colbase + ct * 16 + l15;
    #pragma unroll
    for (int ks = 0; ks < 8; ++ks) {
      const int k0 = ks * 32 + 8 * l4;
      bf16x8 h8, g8;
      #pragma unroll
      for (int j = 0; j < 8; ++j) {
        float w = cW1[(k0 + j) * 256 + n];
        short hi = f2bf(w);
        h8[j] = hi; g8[j] = f2bf(w - bf2f(hi));
      }
      bh[ct][ks] = h8; bl[ct][ks] = g8;
    }
  }
  const int c0 = blockIdx.x, stride = gridDim.x;
  float sob = 0.0f; int sg = 0;
  if (tid < 192) sob = ob[c0 * 192 + tid];
  if (tid < 4)   sg = graph_ids[c0 * 4 + tid];
  __syncthreads();

  for (int c = c0; c < NCHUNK; c += stride) {
    if (tid < 192) obuf[tid] = sob;
    __syncthreads();                              // B1
    if (tid < 64) mfbuf[tid] = ((int)obuf[tid * 3] == 0) ? 1.0f : 0.0f;
    if (tid < 4)  gbuf[tid] = sg;
    int cn = c + stride;
    if (cn < NCHUNK) {
      if (tid < 192) sob = ob[cn * 192 + tid];
      if (tid < 4)   sg = graph_ids[cn * 4 + tid];
    }
    {
      const int kb = tid & 31;
      f32x4 wa0 = w04[kb * 2], wa1 = w04[kb * 2 + 1];
      f32x4 wb0 = w04[64 + kb * 2], wb1 = w04[64 + kb * 2 + 1];
      f32x4 ba0 = b04[kb * 2], ba1 = b04[kb * 2 + 1];
      #pragma unroll
      for (int i = 0; i < 4; ++i) {
        int row = wave * 2 + 16 * i + (lane >> 5);
        float h0 = obuf[row * 3 + 1], h1 = obuf[row * 3 + 2];
        bf16x8 v;
        #pragma unroll
        for (int j = 0; j < 4; ++j) {
          v[j]     = f2bf(fmaxf(fmaf(h0, wa0[j], fmaf(h1, wb0[j], ba0[j])), 0.0f));
          v[4 + j] = f2bf(fmaxf(fmaf(h0, wa1[j], fmaf(h1, wb1[j], ba1[j])), 0.0f));
        }
        *(bf16x8*)(smem + C_ACT1 + row * 512 + ((kb * 16) ^ ((row & 7) << 4))) = v;
      }
    }
    __syncthreads();                              // B2
    const bool evn = (l15 & 1) == 0;
    #pragma unroll 1
    for (int rtp = 0; rtp < 2; ++rtp) {
      f32x4 acc[2][2];
      #pragma unroll
      for (int h = 0; h < 2; ++h)
        #pragma unroll
        for (int ct = 0; ct < 2; ++ct) acc[h][ct] = (f32x4){0.f, 0.f, 0.f, 0.f};
      const int rA0 = rtp * 32 + l15, rA1 = rA0 + 16;
      #pragma unroll
      for (int ks = 0; ks < 8; ++ks) {
        const int cb = (ks * 64 + 16 * l4) ^ swzA;
        bf16x8 a0 = *(const bf16x8*)(smem + C_ACT1 + rA0 * 512 + cb);
        bf16x8 a1 = *(const bf16x8*)(smem + C_ACT1 + rA1 * 512 + cb);
        acc[0][0] = __builtin_amdgcn_mfma_f32_16x16x32_bf16(a0, bh[0][ks], acc[0][0], 0, 0, 0);
        acc[0][1] = __builtin_amdgcn_mfma_f32_16x16x32_bf16(a0, bh[1][ks], acc[0][1], 0, 0, 0);
        acc[1][0] = __builtin_amdgcn_mfma_f32_16x16x32_bf16(a1, bh[0][ks], acc[1][0], 0, 0, 0);
        acc[1][1] = __builtin_amdgcn_mfma_f32_16x16x32_bf16(a1, bh[1][ks], acc[1][1], 0, 0, 0);
        acc[0][0] = __builtin_amdgcn_mfma_f32_16x16x32_bf16(a0, bl[0][ks], acc[0][0], 0, 0, 0);
        acc[0][1] = __builtin_amdgcn_mfma_f32_16x16x32_bf16(a0, bl[1][ks], acc[0][1], 0, 0, 0);
        acc[1][0] = __builtin_amdgcn_mfma_f32_16x16x32_bf16(a1, bl[0][ks], acc[1][0], 0, 0, 0);
        acc[1][1] = __builtin_amdgcn_mfma_f32_16x16x32_bf16(a1, bl[1][ks], acc[1][1], 0, 0, 0);
      }
      #pragma unroll
      for (int ct = 0; ct < 2; ++ct) {
        const int colb = (colbase + ct * 16 + (l15 & ~1)) * 2;
        #pragma unroll
        for (int r = 0; r < 4; ++r) {
          float v0 = fmaxf(acc[0][ct][r] + b1lane[ct], 0.0f);
          float v1 = fmaxf(acc[1][ct][r] + b1lane[ct], 0.0f);
          float n0 = dppf<0xB1>(v0), n1 = dppf<0xB1>(v1);
          uint32_t w = cvt_pk_bf16(evn ? v0 : n1, evn ? n0 : v1);
          int rr = rtp * 32 + (evn ? 0 : 16) + 4 * l4 + r;
          int swzE = ((4 * l4 + r) & 7) << 4;
          *(uint32_t*)(smem + C_ACT2 + rr * 512 + (colb ^ swzE)) = w;
        }
      }
    }
    __syncthreads();                              // B3
    // --- P4: VALU head, all 8 waves (thread: row=tid>>3, col-chunk cc=tid&7) ---
    {
      const int row = tid >> 3, cc = tid & 7;
      const int swzR = ((row & 7) << 4);
      float val = 0.0f;
      #pragma unroll
      for (int q = 0; q < 4; ++q) {
        bf16x8 a = *(const bf16x8*)(smem + C_ACT2 + row * 512 + ((cc * 64 + q * 16) ^ swzR));
        f32x4 wA = w24[cc * 8 + q * 2], wB = w24[cc * 8 + q * 2 + 1];
        #pragma unroll
        for (int j = 0; j < 4; ++j) {
          val = fmaf(bf2f(a[j]), wA[j], val);
          val = fmaf(bf2f(a[4 + j]), wB[j], val);
        }
      }
      val = red8_sum(val);
      if (cc == 0) {
        float mfr = mfbuf[row];
        if (mfr != 0.0f) {
          int g = gbuf[row >> 4];
          atomicAdd(&out[OUT_VP + g * 16 + (row & 15)], (val + cb2v) * (1.0f / 50000.0f));
        }
      }
    }
    const int unused = c; (void)unused;
  }
}

extern "C" void kernel_launch(void* const* d_in, const int* in_sizes, int n_in,
                              void* d_out, int out_size, void* d_ws, size_t ws_size,
                              hipStream_t stream) {
  const float* ob     = (const float*)d_in[0];
  const int*   action = (const int*)d_in[1];
  const int*   gids   = (const int*)d_in[2];
  const float* aW0 = (const float*)d_in[3],  *ab0 = (const float*)d_in[4];
  const float* aW1 = (const float*)d_in[5],  *ab1 = (const float*)d_in[6];
  const float* aW2 = (const float*)d_in[7],  *ab2 = (const float*)d_in[8];
  const float* cW0 = (const float*)d_in[9],  *cb0 = (const float*)d_in[10];
  const float* cW1 = (const float*)d_in[11], *cb1 = (const float*)d_in[12];
  const float* cW2 = (const float*)d_in[13], *cb2 = (const float*)d_in[14];
  float* out = (float*)d_out;
  float* wsf = (float*)d_ws;

  zero_kernel<<<2, 512, 0, stream>>>(out, wsf);
  ac_actor<<<512, 512, A_SZ, stream>>>(ob, action, aW0, ab0, aW1, ab1, aW2, ab2, out, wsf);
  ac_critic<<<256, 512, C_SZ, stream>>>(ob, gids, cW0, cb0, cW1, cb1, cW2, cb2, out);
  final_kernel<<<1, 64, 0, stream>>>(out, wsf);
}

// Round 4
// 499.011 us; speedup vs baseline: 1.8383x; 1.1704x over previous
//
#include <hip/hip_runtime.h>
#include <stdint.h>

// ActorCritic fused kernels for MI355X (gfx950). Round 4.
//   R3 post-mortem: critic spilled (WRITE_SIZE 32MB on a ~0-write kernel; VGPR
//   capped 128 with 128 VGPRs of hi/lo fragments) and sat at 1 block/CU.
//   R4: critic hi-only bf16 (error budget: vp bias ~1e-4 vs ~1e-3 threshold),
//       identical structure to actor -> no spill, 2 blocks/CU both kernels;
//       2 barriers/chunk (double-buffered obuf, P4 reads ob/action/gids global);
//       swizzle SWZ(row)=((row&7)<<4)^((row&16)<<1) (epilogue stores 2-way-free);
//       critic head uses A-frag read pattern (rows=l15) + shfl_xor(16/32) reduce.

typedef __attribute__((ext_vector_type(8))) short bf16x8;
typedef __attribute__((ext_vector_type(4))) float f32x4;

#define NROWS    800000
#define NCHUNK   12500      // NROWS / 64
#define OUT_ENT  800000
#define OUT_VP   800001     // 1024 floats (G=64 x S=16)
#define OUT_MASK 801025     // 800000 floats

#define SWZ(row) ((((row) & 7) << 4) ^ (((row) & 16) << 1))

__device__ __forceinline__ short f2bf(float x) {            // RNE float->bf16
  union { float f; uint32_t u; } v; v.f = x;
  return (short)(uint16_t)((v.u + 0x7FFFu + ((v.u >> 16) & 1u)) >> 16);
}
__device__ __forceinline__ float bf2f(short h) {
  union { uint32_t u; float f; } v; v.u = ((uint32_t)(uint16_t)h) << 16;
  return v.f;
}
// DPP helpers (VALU pipe). quad_perm(1,0,3,2)=0xB1, quad_perm(2,3,0,1)=0x4E,
// ROW_ROR:4=0x124, ROW_ROR:8=0x128.
template <int C>
__device__ __forceinline__ float dppf(float x) {
  int r = __builtin_amdgcn_update_dpp(0, __builtin_bit_cast(int, x), C, 0xF, 0xF, true);
  return __builtin_bit_cast(float, r);
}
__device__ __forceinline__ float red16_sum(float x) {
  x += dppf<0xB1>(x); x += dppf<0x4E>(x); x += dppf<0x124>(x); x += dppf<0x128>(x); return x;
}
__device__ __forceinline__ float red16_max(float x) {
  x = fmaxf(x, dppf<0xB1>(x)); x = fmaxf(x, dppf<0x4E>(x));
  x = fmaxf(x, dppf<0x124>(x)); x = fmaxf(x, dppf<0x128>(x)); return x;
}
__device__ __forceinline__ uint32_t cvt_pk_bf16(float a, float b) {   // lo=bf16(a), hi=bf16(b)
  uint32_t r; asm("v_cvt_pk_bf16_f32 %0, %1, %2" : "=v"(r) : "v"(a), "v"(b)); return r;
}

__global__ void zero_kernel(float* out, float* wsf) {
  int t = threadIdx.x + blockIdx.x * blockDim.x;
  for (int i = t; i < 1025; i += 1024) out[OUT_ENT + i] = 0.0f;
  if (t == 0) { wsf[0] = 0.0f; wsf[1] = 0.0f; }
}
__global__ void final_kernel(float* out, const float* wsf) {
  if (threadIdx.x == 0 && blockIdx.x == 0)
    out[OUT_ENT] = (wsf[1] > 0.0f) ? (wsf[0] / wsf[1]) : 0.0f;
}

// ---------------- actor LDS (78848 B -> 2 blocks/CU) ----------------
#define A_ACT1 0          // [64][256] bf16 swizzled (32768)
#define A_ACT2 32768      // [64][256] bf16 swizzled (32768)
#define A_W2H  65536      // [16][256] bf16 swizzled (8192)
#define A_W0   73728      // [2][256] f32 (2048)
#define A_B0   75776      // [256] f32 (1024)
#define A_OB   76800      // 2 x [192(+pad)] f32 (2048)
#define A_SZ   78848

__global__ void __launch_bounds__(512, 4) ac_actor(
    const float* __restrict__ ob, const int* __restrict__ action,
    const float* __restrict__ aW0, const float* __restrict__ ab0,
    const float* __restrict__ aW1, const float* __restrict__ ab1,
    const float* __restrict__ aW2, const float* __restrict__ ab2,
    float* __restrict__ out, float* __restrict__ wsf)
{
  extern __shared__ char smem[];
  float* w0buf = (float*)(smem + A_W0);
  float* b0buf = (float*)(smem + A_B0);
  float* obufA = (float*)(smem + A_OB);          // two 256-float buffers
  const f32x4* w04 = (const f32x4*)(smem + A_W0);
  const f32x4* b04 = (const f32x4*)(smem + A_B0);
  __shared__ float went[8], wmf[8];

  const int tid = threadIdx.x, lane = tid & 63, wave = tid >> 6;
  const int l15 = lane & 15, l4 = lane >> 4;

  // setup
  w0buf[tid] = aW0[tid];
  if (tid < 256) b0buf[tid] = ab0[tid];
  for (int id = tid; id < 4096; id += 512) {      // W2 hi -> swizzled LDS
    int n = id >> 8, k = id & 255;
    *(short*)(smem + A_W2H + n * 512 + ((k * 2) ^ SWZ(n))) = f2bf(aW2[k * 16 + n]);
  }
  const int colbase = wave * 32;
  float b1lane[2] = { ab1[colbase + l15], ab1[colbase + 16 + l15] };
  float b2lane = ab2[l15];
  bf16x8 bh[2][8];                                // W1 hi fragments, register-resident
  #pragma unroll
  for (int ct = 0; ct < 2; ++ct) {
    const int n = colbase + ct * 16 + l15;
    #pragma unroll
    for (int ks = 0; ks < 8; ++ks) {
      const int k0 = ks * 32 + 8 * l4;
      bf16x8 h8;
      #pragma unroll
      for (int j = 0; j < 8; ++j) h8[j] = f2bf(aW1[(k0 + j) * 256 + n]);
      bh[ct][ks] = h8;
    }
  }
  // prologue: land chunk c0 into buf 0, start load of c0+stride
  const int c0 = blockIdx.x, stride = gridDim.x;
  float sob = 0.0f;
  if (tid < 192) { obufA[tid] = ob[c0 * 192 + tid]; }
  { int cn = c0 + stride; if (cn < NCHUNK && tid < 192) sob = ob[cn * 192 + tid]; }
  __syncthreads();

  float entacc = 0.0f, mfacc = 0.0f;
  int buf = 0;
  for (int c = c0; c < NCHUNK; c += stride, buf ^= 1) {
    const int row0 = c * 64;
    const float* ocur = obufA + buf * 256;
    float* onxt = (float*)(obufA + (buf ^ 1) * 256);

    // --- P2: mask out + act1 = relu(h@W0+b0); stage next ob ---
    if (tid < 64) out[OUT_MASK + row0 + tid] = ((int)ocur[tid * 3] == 0) ? 1.0f : 0.0f;
    {
      const int kb = tid & 31;
      f32x4 wa0 = w04[kb * 2], wa1 = w04[kb * 2 + 1];
      f32x4 wb0 = w04[64 + kb * 2], wb1 = w04[64 + kb * 2 + 1];
      f32x4 ba0 = b04[kb * 2], ba1 = b04[kb * 2 + 1];
      #pragma unroll
      for (int i = 0; i < 4; ++i) {
        int row = wave * 2 + 16 * i + (lane >> 5);
        float h0 = ocur[row * 3 + 1], h1 = ocur[row * 3 + 2];
        bf16x8 v;
        #pragma unroll
        for (int j = 0; j < 4; ++j) {
          v[j]     = f2bf(fmaxf(fmaf(h0, wa0[j], fmaf(h1, wb0[j], ba0[j])), 0.0f));
          v[4 + j] = f2bf(fmaxf(fmaf(h0, wa1[j], fmaf(h1, wb1[j], ba1[j])), 0.0f));
        }
        *(bf16x8*)(smem + A_ACT1 + row * 512 + ((kb * 16) ^ SWZ(row))) = v;
      }
    }
    if (tid < 192) onxt[tid] = sob;               // stage chunk c+stride
    { int c2 = c + 2 * stride; if (c2 < NCHUNK && tid < 192) sob = ob[c2 * 192 + tid]; }
    __syncthreads();                              // B2: act1 + onxt ready

    // --- P3: GEMM1 256x256 + epilogue -> act2 ---
    const bool evn = (l15 & 1) == 0;
    #pragma unroll 1
    for (int rtp = 0; rtp < 2; ++rtp) {
      f32x4 acc[2][2];
      #pragma unroll
      for (int h = 0; h < 2; ++h)
        #pragma unroll
        for (int ct = 0; ct < 2; ++ct) acc[h][ct] = (f32x4){0.f, 0.f, 0.f, 0.f};
      const int rA0 = rtp * 32 + l15, rA1 = rA0 + 16;
      #pragma unroll
      for (int ks = 0; ks < 8; ++ks) {
        const int cb = ks * 64 + 16 * l4;
        bf16x8 a0 = *(const bf16x8*)(smem + A_ACT1 + rA0 * 512 + (cb ^ SWZ(rA0)));
        bf16x8 a1 = *(const bf16x8*)(smem + A_ACT1 + rA1 * 512 + (cb ^ SWZ(rA1)));
        acc[0][0] = __builtin_amdgcn_mfma_f32_16x16x32_bf16(a0, bh[0][ks], acc[0][0], 0, 0, 0);
        acc[0][1] = __builtin_amdgcn_mfma_f32_16x16x32_bf16(a0, bh[1][ks], acc[0][1], 0, 0, 0);
        acc[1][0] = __builtin_amdgcn_mfma_f32_16x16x32_bf16(a1, bh[0][ks], acc[1][0], 0, 0, 0);
        acc[1][1] = __builtin_amdgcn_mfma_f32_16x16x32_bf16(a1, bh[1][ks], acc[1][1], 0, 0, 0);
      }
      #pragma unroll
      for (int ct = 0; ct < 2; ++ct) {
        const int colb = (colbase + ct * 16 + (l15 & ~1)) * 2;
        #pragma unroll
        for (int r = 0; r < 4; ++r) {
          float v0 = fmaxf(acc[0][ct][r] + b1lane[ct], 0.0f);
          float v1 = fmaxf(acc[1][ct][r] + b1lane[ct], 0.0f);
          float n0 = dppf<0xB1>(v0), n1 = dppf<0xB1>(v1);
          uint32_t w = cvt_pk_bf16(evn ? v0 : n1, evn ? n0 : v1);
          int rr = rtp * 32 + (evn ? 0 : 16) + 4 * l4 + r;
          *(uint32_t*)(smem + A_ACT2 + rr * 512 + (colb ^ SWZ(rr))) = w;
        }
      }
    }
    __syncthreads();                              // B3: act2 ready

    // --- P4: head GEMM + log-softmax (waves 0-3) ---
    if (wave < 4) {
      const int rowA = wave * 16 + l15;
      const int swA = SWZ(rowA), swW = SWZ(l15);
      f32x4 ae = {0.f,0.f,0.f,0.f}, ao = {0.f,0.f,0.f,0.f};
      #pragma unroll
      for (int ks = 0; ks < 8; ks += 2) {
        const int cb0 = ks * 64 + 16 * l4, cb1 = cb0 + 64;
        bf16x8 a0 = *(const bf16x8*)(smem + A_ACT2 + rowA * 512 + (cb0 ^ swA));
        bf16x8 a1 = *(const bf16x8*)(smem + A_ACT2 + rowA * 512 + (cb1 ^ swA));
        bf16x8 w0f = *(const bf16x8*)(smem + A_W2H + l15 * 512 + (cb0 ^ swW));
        bf16x8 w1f = *(const bf16x8*)(smem + A_W2H + l15 * 512 + (cb1 ^ swW));
        ae = __builtin_amdgcn_mfma_f32_16x16x32_bf16(a0, w0f, ae, 0, 0, 0);
        ao = __builtin_amdgcn_mfma_f32_16x16x32_bf16(a1, w1f, ao, 0, 0, 0);
      }
      #pragma unroll
      for (int r = 0; r < 4; ++r) {
        const int rl = wave * 16 + 4 * l4 + r;
        float x = ae[r] + ao[r] + b2lane;
        float m = red16_max(x);
        float e = __expf(x - m);
        float s = red16_sum(e);
        float t = red16_sum(e * (x - m));
        float ls = __logf(s);
        float mfr = ((int)ob[(row0 + rl) * 3] == 0) ? 1.0f : 0.0f;
        int av = action[row0 + rl];
        if (l15 == av) out[row0 + rl] = (x - m - ls) * mfr;
        if (l15 == 0) { entacc += (ls - t / s) * mfr; mfacc += mfr; }
      }
    }
    // no end barrier: next P2 touches act1/obuf only; act1 last read before B3,
    // obuf[cur^1] write fenced by B2+B3 before its next read.
  }
  // entropy num/den -> global atomics
  #pragma unroll
  for (int d = 1; d < 64; d <<= 1) { entacc += __shfl_xor(entacc, d); mfacc += __shfl_xor(mfacc, d); }
  if (lane == 0) { went[wave] = entacc; wmf[wave] = mfacc; }
  __syncthreads();
  if (tid == 0) {
    float e = 0.f, m = 0.f;
    #pragma unroll
    for (int i = 0; i < 8; ++i) { e += went[i]; m += wmf[i]; }
    atomicAdd(&wsf[0], e); atomicAdd(&wsf[1], m);
  }
}

// ---------------- critic LDS (71680 B -> 2 blocks/CU) ----------------
#define C_ACT1 0
#define C_ACT2 32768
#define C_W0   65536      // 2048
#define C_B0   67584      // 1024
#define C_W2F  68608      // [256] f32 (1024)
#define C_OB   69632      // 2 x 1024
#define C_SZ   71680

__global__ void __launch_bounds__(512, 4) ac_critic(
    const float* __restrict__ ob, const int* __restrict__ graph_ids,
    const float* __restrict__ cW0, const float* __restrict__ cb0,
    const float* __restrict__ cW1, const float* __restrict__ cb1,
    const float* __restrict__ cW2, const float* __restrict__ cb2,
    float* __restrict__ out)
{
  extern __shared__ char smem[];
  float* w0buf = (float*)(smem + C_W0);
  float* b0buf = (float*)(smem + C_B0);
  float* w2buf = (float*)(smem + C_W2F);
  float* obufA = (float*)(smem + C_OB);
  const f32x4* w04 = (const f32x4*)(smem + C_W0);
  const f32x4* b04 = (const f32x4*)(smem + C_B0);
  const f32x4* w24 = (const f32x4*)(smem + C_W2F);

  const int tid = threadIdx.x, lane = tid & 63, wave = tid >> 6;
  const int l15 = lane & 15, l4 = lane >> 4;

  w0buf[tid] = cW0[tid];
  if (tid < 256) b0buf[tid] = cb0[tid];
  if (tid >= 256 && tid < 512) w2buf[tid - 256] = cW2[tid - 256];
  const float cb2v = cb2[0];
  const int colbase = wave * 32;
  float b1lane[2] = { cb1[colbase + l15], cb1[colbase + 16 + l15] };

  bf16x8 bh[2][8];                                // W1 hi-only (no spill, fits 128 VGPR)
  #pragma unroll
  for (int ct = 0; ct < 2; ++ct) {
    const int n = colbase + ct * 16 + l15;
    #pragma unroll
    for (int ks = 0; ks < 8; ++ks) {
      const int k0 = ks * 32 + 8 * l4;
      bf16x8 h8;
      #pragma unroll
      for (int j = 0; j < 8; ++j) h8[j] = f2bf(cW1[(k0 + j) * 256 + n]);
      bh[ct][ks] = h8;
    }
  }
  const int c0 = blockIdx.x, stride = gridDim.x;
  float sob = 0.0f;
  if (tid < 192) { obufA[tid] = ob[c0 * 192 + tid]; }
  { int cn = c0 + stride; if (cn < NCHUNK && tid < 192) sob = ob[cn * 192 + tid]; }
  __syncthreads();

  int buf = 0;
  for (int c = c0; c < NCHUNK; c += stride, buf ^= 1) {
    const int row0 = c * 64;
    const float* ocur = obufA + buf * 256;
    float* onxt = (float*)(obufA + (buf ^ 1) * 256);

    // --- P2 ---
    {
      const int kb = tid & 31;
      f32x4 wa0 = w04[kb * 2], wa1 = w04[kb * 2 + 1];
      f32x4 wb0 = w04[64 + kb * 2], wb1 = w04[64 + kb * 2 + 1];
      f32x4 ba0 = b04[kb * 2], ba1 = b04[kb * 2 + 1];
      #pragma unroll
      for (int i = 0; i < 4; ++i) {
        int row = wave * 2 + 16 * i + (lane >> 5);
        float h0 = ocur[row * 3 + 1], h1 = ocur[row * 3 + 2];
        bf16x8 v;
        #pragma unroll
        for (int j = 0; j < 4; ++j) {
          v[j]     = f2bf(fmaxf(fmaf(h0, wa0[j], fmaf(h1, wb0[j], ba0[j])), 0.0f));
          v[4 + j] = f2bf(fmaxf(fmaf(h0, wa1[j], fmaf(h1, wb1[j], ba1[j])), 0.0f));
        }
        *(bf16x8*)(smem + C_ACT1 + row * 512 + ((kb * 16) ^ SWZ(row))) = v;
      }
    }
    if (tid < 192) onxt[tid] = sob;
    { int c2 = c + 2 * stride; if (c2 < NCHUNK && tid < 192) sob = ob[c2 * 192 + tid]; }
    __syncthreads();                              // B2

    // --- P3 ---
    const bool evn = (l15 & 1) == 0;
    #pragma unroll 1
    for (int rtp = 0; rtp < 2; ++rtp) {
      f32x4 acc[2][2];
      #pragma unroll
      for (int h = 0; h < 2; ++h)
        #pragma unroll
        for (int ct = 0; ct < 2; ++ct) acc[h][ct] = (f32x4){0.f, 0.f, 0.f, 0.f};
      const int rA0 = rtp * 32 + l15, rA1 = rA0 + 16;
      #pragma unroll
      for (int ks = 0; ks < 8; ++ks) {
        const int cb = ks * 64 + 16 * l4;
        bf16x8 a0 = *(const bf16x8*)(smem + C_ACT1 + rA0 * 512 + (cb ^ SWZ(rA0)));
        bf16x8 a1 = *(const bf16x8*)(smem + C_ACT1 + rA1 * 512 + (cb ^ SWZ(rA1)));
        acc[0][0] = __builtin_amdgcn_mfma_f32_16x16x32_bf16(a0, bh[0][ks], acc[0][0], 0, 0, 0);
        acc[0][1] = __builtin_amdgcn_mfma_f32_16x16x32_bf16(a0, bh[1][ks], acc[0][1], 0, 0, 0);
        acc[1][0] = __builtin_amdgcn_mfma_f32_16x16x32_bf16(a1, bh[0][ks], acc[1][0], 0, 0, 0);
        acc[1][1] = __builtin_amdgcn_mfma_f32_16x16x32_bf16(a1, bh[1][ks], acc[1][1], 0, 0, 0);
      }
      #pragma unroll
      for (int ct = 0; ct < 2; ++ct) {
        const int colb = (colbase + ct * 16 + (l15 & ~1)) * 2;
        #pragma unroll
        for (int r = 0; r < 4; ++r) {
          float v0 = fmaxf(acc[0][ct][r] + b1lane[ct], 0.0f);
          float v1 = fmaxf(acc[1][ct][r] + b1lane[ct], 0.0f);
          float n0 = dppf<0xB1>(v0), n1 = dppf<0xB1>(v1);
          uint32_t w = cvt_pk_bf16(evn ? v0 : n1, evn ? n0 : v1);
          int rr = rtp * 32 + (evn ? 0 : 16) + 4 * l4 + r;
          *(uint32_t*)(smem + C_ACT2 + rr * 512 + (colb ^ SWZ(rr))) = w;
        }
      }
    }
    __syncthreads();                              // B3

    // --- P4: VALU head, waves 0-3, A-frag read pattern (rows = l15, 2-way-free) ---
    if (wave < 4) {
      const int rt = wave;
      const int row = rt * 16 + l15;
      const int sw = SWZ(row);
      float val = 0.0f;
      #pragma unroll
      for (int ks = 0; ks < 8; ++ks) {
        bf16x8 a = *(const bf16x8*)(smem + C_ACT2 + row * 512 + ((ks * 64 + 16 * l4) ^ sw));
        f32x4 wA = w24[ks * 8 + 2 * l4], wB = w24[ks * 8 + 2 * l4 + 1];
        #pragma unroll
        for (int j = 0; j < 4; ++j) {
          val = fmaf(bf2f(a[j]), wA[j], val);
          val = fmaf(bf2f(a[4 + j]), wB[j], val);
        }
      }
      val += __shfl_xor(val, 16);                 // reduce over l4 (k-slices)
      val += __shfl_xor(val, 32);
      if (l4 == 0) {
        float o0 = ob[(row0 + row) * 3];
        if ((int)o0 == 0) {
          int g = graph_ids[c * 4 + rt];
          atomicAdd(&out[OUT_VP + g * 16 + l15], (val + cb2v) * (1.0f / 50000.0f));
        }
      }
    }
  }
}

extern "C" void kernel_launch(void* const* d_in, const int* in_sizes, int n_in,
                              void* d_out, int out_size, void* d_ws, size_t ws_size,
                              hipStream_t stream) {
  const float* ob     = (const float*)d_in[0];
  const int*   action = (const int*)d_in[1];
  const int*   gids   = (const int*)d_in[2];
  const float* aW0 = (const float*)d_in[3],  *ab0 = (const float*)d_in[4];
  const float* aW1 = (const float*)d_in[5],  *ab1 = (const float*)d_in[6];
  const float* aW2 = (const float*)d_in[7],  *ab2 = (const float*)d_in[8];
  const float* cW0 = (const float*)d_in[9],  *cb0 = (const float*)d_in[10];
  const float* cW1 = (const float*)d_in[11], *cb1 = (const float*)d_in[12];
  const float* cW2 = (const float*)d_in[13], *cb2 = (const float*)d_in[14];
  float* out = (float*)d_out;
  float* wsf = (float*)d_ws;

  zero_kernel<<<2, 512, 0, stream>>>(out, wsf);
  ac_actor<<<512, 512, A_SZ, stream>>>(ob, action, aW0, ab0, aW1, ab1, aW2, ab2, out, wsf);
  ac_critic<<<512, 512, C_SZ, stream>>>(ob, gids, cW0, cb0, cW1, cb1, cW2, cb2, out);
  final_kernel<<<1, 64, 0, stream>>>(out, wsf);
}

// Round 6
// 483.540 us; speedup vs baseline: 1.8971x; 1.0320x over previous
//
#include <hip/hip_runtime.h>
#include <stdint.h>

// ActorCritic fused kernels for MI355X (gfx950). Round 5 resubmit (R5 was a
// GPU-acquisition timeout; no data).
//   R4 post-mortem: __launch_bounds__(512,4) on this hipcc = cap 64 VGPR
//   (empirical: lb(512,2)->128, lb(512,4)->64, i.e. cap=256/N for 512-thr blocks).
//   64-cap under 64 VGPRs of W1 fragments => catastrophic spill (actor WRITE 63.8MB,
//   occupancy 4%). R5: lb(512,2) both (cap 128; audited peak demand ~105, no spill);
//   P2 uses v_cvt_pk_bf16_f32 pairs (fewer VALU ops, fewer temps).

typedef __attribute__((ext_vector_type(8))) short bf16x8;
typedef __attribute__((ext_vector_type(4))) float f32x4;
typedef __attribute__((ext_vector_type(4))) uint32_t u32x4;

#define NROWS    800000
#define NCHUNK   12500      // NROWS / 64
#define OUT_ENT  800000
#define OUT_VP   800001     // 1024 floats (G=64 x S=16)
#define OUT_MASK 801025     // 800000 floats

#define SWZ(row) ((((row) & 7) << 4) ^ (((row) & 16) << 1))

__device__ __forceinline__ short f2bf(float x) {            // RNE float->bf16
  union { float f; uint32_t u; } v; v.f = x;
  return (short)(uint16_t)((v.u + 0x7FFFu + ((v.u >> 16) & 1u)) >> 16);
}
__device__ __forceinline__ float bf2f(short h) {
  union { uint32_t u; float f; } v; v.u = ((uint32_t)(uint16_t)h) << 16;
  return v.f;
}
// DPP helpers (VALU pipe). quad_perm(1,0,3,2)=0xB1, quad_perm(2,3,0,1)=0x4E,
// ROW_ROR:4=0x124, ROW_ROR:8=0x128.
template <int C>
__device__ __forceinline__ float dppf(float x) {
  int r = __builtin_amdgcn_update_dpp(0, __builtin_bit_cast(int, x), C, 0xF, 0xF, true);
  return __builtin_bit_cast(float, r);
}
__device__ __forceinline__ float red16_sum(float x) {
  x += dppf<0xB1>(x); x += dppf<0x4E>(x); x += dppf<0x124>(x); x += dppf<0x128>(x); return x;
}
__device__ __forceinline__ float red16_max(float x) {
  x = fmaxf(x, dppf<0xB1>(x)); x = fmaxf(x, dppf<0x4E>(x));
  x = fmaxf(x, dppf<0x124>(x)); x = fmaxf(x, dppf<0x128>(x)); return x;
}
__device__ __forceinline__ uint32_t cvt_pk_bf16(float a, float b) {   // lo=bf16(a), hi=bf16(b)
  uint32_t r; asm("v_cvt_pk_bf16_f32 %0, %1, %2" : "=v"(r) : "v"(a), "v"(b)); return r;
}

__global__ void zero_kernel(float* out, float* wsf) {
  int t = threadIdx.x + blockIdx.x * blockDim.x;
  for (int i = t; i < 1025; i += 1024) out[OUT_ENT + i] = 0.0f;
  if (t == 0) { wsf[0] = 0.0f; wsf[1] = 0.0f; }
}
__global__ void final_kernel(float* out, const float* wsf) {
  if (threadIdx.x == 0 && blockIdx.x == 0)
    out[OUT_ENT] = (wsf[1] > 0.0f) ? (wsf[0] / wsf[1]) : 0.0f;
}

// ---------------- actor LDS (78848 B -> 2 blocks/CU) ----------------
#define A_ACT1 0          // [64][256] bf16 swizzled (32768)
#define A_ACT2 32768      // [64][256] bf16 swizzled (32768)
#define A_W2H  65536      // [16][256] bf16 swizzled (8192)
#define A_W0   73728      // [2][256] f32 (2048)
#define A_B0   75776      // [256] f32 (1024)
#define A_OB   76800      // 2 x [192(+pad)] f32 (2048)
#define A_SZ   78848

__global__ void __launch_bounds__(512, 2) ac_actor(
    const float* __restrict__ ob, const int* __restrict__ action,
    const float* __restrict__ aW0, const float* __restrict__ ab0,
    const float* __restrict__ aW1, const float* __restrict__ ab1,
    const float* __restrict__ aW2, const float* __restrict__ ab2,
    float* __restrict__ out, float* __restrict__ wsf)
{
  extern __shared__ char smem[];
  float* w0buf = (float*)(smem + A_W0);
  float* b0buf = (float*)(smem + A_B0);
  float* obufA = (float*)(smem + A_OB);          // two 256-float buffers
  const f32x4* w04 = (const f32x4*)(smem + A_W0);
  const f32x4* b04 = (const f32x4*)(smem + A_B0);
  __shared__ float went[8], wmf[8];

  const int tid = threadIdx.x, lane = tid & 63, wave = tid >> 6;
  const int l15 = lane & 15, l4 = lane >> 4;

  // setup
  w0buf[tid] = aW0[tid];
  if (tid < 256) b0buf[tid] = ab0[tid];
  for (int id = tid; id < 4096; id += 512) {      // W2 hi -> swizzled LDS
    int n = id >> 8, k = id & 255;
    *(short*)(smem + A_W2H + n * 512 + ((k * 2) ^ SWZ(n))) = f2bf(aW2[k * 16 + n]);
  }
  const int colbase = wave * 32;
  float b1lane[2] = { ab1[colbase + l15], ab1[colbase + 16 + l15] };
  float b2lane = ab2[l15];
  bf16x8 bh[2][8];                                // W1 hi fragments, register-resident
  #pragma unroll
  for (int ct = 0; ct < 2; ++ct) {
    const int n = colbase + ct * 16 + l15;
    #pragma unroll
    for (int ks = 0; ks < 8; ++ks) {
      const int k0 = ks * 32 + 8 * l4;
      bf16x8 h8;
      #pragma unroll
      for (int j = 0; j < 8; ++j) h8[j] = f2bf(aW1[(k0 + j) * 256 + n]);
      bh[ct][ks] = h8;
    }
  }
  // prologue: land chunk c0 into buf 0, start load of c0+stride
  const int c0 = blockIdx.x, stride = gridDim.x;
  float sob = 0.0f;
  if (tid < 192) { obufA[tid] = ob[c0 * 192 + tid]; }
  { int cn = c0 + stride; if (cn < NCHUNK && tid < 192) sob = ob[cn * 192 + tid]; }
  __syncthreads();

  float entacc = 0.0f, mfacc = 0.0f;
  int buf = 0;
  for (int c = c0; c < NCHUNK; c += stride, buf ^= 1) {
    const int row0 = c * 64;
    const float* ocur = obufA + buf * 256;
    float* onxt = (float*)(obufA + (buf ^ 1) * 256);

    // --- P2: mask out + act1 = relu(h@W0+b0); stage next ob ---
    if (tid < 64) out[OUT_MASK + row0 + tid] = ((int)ocur[tid * 3] == 0) ? 1.0f : 0.0f;
    {
      const int kb = tid & 31;
      f32x4 wa0 = w04[kb * 2], wa1 = w04[kb * 2 + 1];
      f32x4 wb0 = w04[64 + kb * 2], wb1 = w04[64 + kb * 2 + 1];
      f32x4 ba0 = b04[kb * 2], ba1 = b04[kb * 2 + 1];
      #pragma unroll
      for (int i = 0; i < 4; ++i) {
        int row = wave * 2 + 16 * i + (lane >> 5);
        float h0 = ocur[row * 3 + 1], h1 = ocur[row * 3 + 2];
        f32x4 va, vb;
        #pragma unroll
        for (int j = 0; j < 4; ++j) {
          va[j] = fmaxf(fmaf(h0, wa0[j], fmaf(h1, wb0[j], ba0[j])), 0.0f);
          vb[j] = fmaxf(fmaf(h0, wa1[j], fmaf(h1, wb1[j], ba1[j])), 0.0f);
        }
        u32x4 v;
        v[0] = cvt_pk_bf16(va[0], va[1]);
        v[1] = cvt_pk_bf16(va[2], va[3]);
        v[2] = cvt_pk_bf16(vb[0], vb[1]);
        v[3] = cvt_pk_bf16(vb[2], vb[3]);
        *(u32x4*)(smem + A_ACT1 + row * 512 + ((kb * 16) ^ SWZ(row))) = v;
      }
    }
    if (tid < 192) onxt[tid] = sob;               // stage chunk c+stride
    { int c2 = c + 2 * stride; if (c2 < NCHUNK && tid < 192) sob = ob[c2 * 192 + tid]; }
    __syncthreads();                              // B2: act1 + onxt ready

    // --- P3: GEMM1 256x256 + epilogue -> act2 ---
    const bool evn = (l15 & 1) == 0;
    #pragma unroll 1
    for (int rtp = 0; rtp < 2; ++rtp) {
      f32x4 acc[2][2];
      #pragma unroll
      for (int h = 0; h < 2; ++h)
        #pragma unroll
        for (int ct = 0; ct < 2; ++ct) acc[h][ct] = (f32x4){0.f, 0.f, 0.f, 0.f};
      const int rA0 = rtp * 32 + l15, rA1 = rA0 + 16;
      #pragma unroll
      for (int ks = 0; ks < 8; ++ks) {
        const int cb = ks * 64 + 16 * l4;
        bf16x8 a0 = *(const bf16x8*)(smem + A_ACT1 + rA0 * 512 + (cb ^ SWZ(rA0)));
        bf16x8 a1 = *(const bf16x8*)(smem + A_ACT1 + rA1 * 512 + (cb ^ SWZ(rA1)));
        acc[0][0] = __builtin_amdgcn_mfma_f32_16x16x32_bf16(a0, bh[0][ks], acc[0][0], 0, 0, 0);
        acc[0][1] = __builtin_amdgcn_mfma_f32_16x16x32_bf16(a0, bh[1][ks], acc[0][1], 0, 0, 0);
        acc[1][0] = __builtin_amdgcn_mfma_f32_16x16x32_bf16(a1, bh[0][ks], acc[1][0], 0, 0, 0);
        acc[1][1] = __builtin_amdgcn_mfma_f32_16x16x32_bf16(a1, bh[1][ks], acc[1][1], 0, 0, 0);
      }
      #pragma unroll
      for (int ct = 0; ct < 2; ++ct) {
        const int colb = (colbase + ct * 16 + (l15 & ~1)) * 2;
        #pragma unroll
        for (int r = 0; r < 4; ++r) {
          float v0 = fmaxf(acc[0][ct][r] + b1lane[ct], 0.0f);
          float v1 = fmaxf(acc[1][ct][r] + b1lane[ct], 0.0f);
          float n0 = dppf<0xB1>(v0), n1 = dppf<0xB1>(v1);
          uint32_t w = cvt_pk_bf16(evn ? v0 : n1, evn ? n0 : v1);
          int rr = rtp * 32 + (evn ? 0 : 16) + 4 * l4 + r;
          *(uint32_t*)(smem + A_ACT2 + rr * 512 + (colb ^ SWZ(rr))) = w;
        }
      }
    }
    __syncthreads();                              // B3: act2 ready

    // --- P4: head GEMM + log-softmax (waves 0-3) ---
    if (wave < 4) {
      const int rowA = wave * 16 + l15;
      const int swA = SWZ(rowA), swW = SWZ(l15);
      f32x4 ae = {0.f,0.f,0.f,0.f}, ao = {0.f,0.f,0.f,0.f};
      #pragma unroll
      for (int ks = 0; ks < 8; ks += 2) {
        const int cb0 = ks * 64 + 16 * l4, cb1 = cb0 + 64;
        bf16x8 a0 = *(const bf16x8*)(smem + A_ACT2 + rowA * 512 + (cb0 ^ swA));
        bf16x8 a1 = *(const bf16x8*)(smem + A_ACT2 + rowA * 512 + (cb1 ^ swA));
        bf16x8 w0f = *(const bf16x8*)(smem + A_W2H + l15 * 512 + (cb0 ^ swW));
        bf16x8 w1f = *(const bf16x8*)(smem + A_W2H + l15 * 512 + (cb1 ^ swW));
        ae = __builtin_amdgcn_mfma_f32_16x16x32_bf16(a0, w0f, ae, 0, 0, 0);
        ao = __builtin_amdgcn_mfma_f32_16x16x32_bf16(a1, w1f, ao, 0, 0, 0);
      }
      #pragma unroll
      for (int r = 0; r < 4; ++r) {
        const int rl = wave * 16 + 4 * l4 + r;
        float x = ae[r] + ao[r] + b2lane;
        float m = red16_max(x);
        float e = __expf(x - m);
        float s = red16_sum(e);
        float t = red16_sum(e * (x - m));
        float ls = __logf(s);
        float mfr = ((int)ob[(row0 + rl) * 3] == 0) ? 1.0f : 0.0f;
        int av = action[row0 + rl];
        if (l15 == av) out[row0 + rl] = (x - m - ls) * mfr;
        if (l15 == 0) { entacc += (ls - t / s) * mfr; mfacc += mfr; }
      }
    }
    // no end barrier: next P2 touches act1/obuf only (disjoint from P4's act2/W2H
    // reads); obuf buffers are fenced by B2+B3 between write and read.
  }
  // entropy num/den -> global atomics
  #pragma unroll
  for (int d = 1; d < 64; d <<= 1) { entacc += __shfl_xor(entacc, d); mfacc += __shfl_xor(mfacc, d); }
  if (lane == 0) { went[wave] = entacc; wmf[wave] = mfacc; }
  __syncthreads();
  if (tid == 0) {
    float e = 0.f, m = 0.f;
    #pragma unroll
    for (int i = 0; i < 8; ++i) { e += went[i]; m += wmf[i]; }
    atomicAdd(&wsf[0], e); atomicAdd(&wsf[1], m);
  }
}

// ---------------- critic LDS (71680 B -> 2 blocks/CU) ----------------
#define C_ACT1 0
#define C_ACT2 32768
#define C_W0   65536      // 2048
#define C_B0   67584      // 1024
#define C_W2F  68608      // [256] f32 (1024)
#define C_OB   69632      // 2 x 1024
#define C_SZ   71680

__global__ void __launch_bounds__(512, 2) ac_critic(
    const float* __restrict__ ob, const int* __restrict__ graph_ids,
    const float* __restrict__ cW0, const float* __restrict__ cb0,
    const float* __restrict__ cW1, const float* __restrict__ cb1,
    const float* __restrict__ cW2, const float* __restrict__ cb2,
    float* __restrict__ out)
{
  extern __shared__ char smem[];
  float* w0buf = (float*)(smem + C_W0);
  float* b0buf = (float*)(smem + C_B0);
  float* w2buf = (float*)(smem + C_W2F);
  float* obufA = (float*)(smem + C_OB);
  const f32x4* w04 = (const f32x4*)(smem + C_W0);
  const f32x4* b04 = (const f32x4*)(smem + C_B0);
  const f32x4* w24 = (const f32x4*)(smem + C_W2F);

  const int tid = threadIdx.x, lane = tid & 63, wave = tid >> 6;
  const int l15 = lane & 15, l4 = lane >> 4;

  w0buf[tid] = cW0[tid];
  if (tid < 256) b0buf[tid] = cb0[tid];
  if (tid >= 256 && tid < 512) w2buf[tid - 256] = cW2[tid - 256];
  const float cb2v = cb2[0];
  const int colbase = wave * 32;
  float b1lane[2] = { cb1[colbase + l15], cb1[colbase + 16 + l15] };

  bf16x8 bh[2][8];                                // W1 hi-only, register-resident
  #pragma unroll
  for (int ct = 0; ct < 2; ++ct) {
    const int n = colbase + ct * 16 + l15;
    #pragma unroll
    for (int ks = 0; ks < 8; ++ks) {
      const int k0 = ks * 32 + 8 * l4;
      bf16x8 h8;
      #pragma unroll
      for (int j = 0; j < 8; ++j) h8[j] = f2bf(cW1[(k0 + j) * 256 + n]);
      bh[ct][ks] = h8;
    }
  }
  const int c0 = blockIdx.x, stride = gridDim.x;
  float sob = 0.0f;
  if (tid < 192) { obufA[tid] = ob[c0 * 192 + tid]; }
  { int cn = c0 + stride; if (cn < NCHUNK && tid < 192) sob = ob[cn * 192 + tid]; }
  __syncthreads();

  int buf = 0;
  for (int c = c0; c < NCHUNK; c += stride, buf ^= 1) {
    const int row0 = c * 64;
    const float* ocur = obufA + buf * 256;
    float* onxt = (float*)(obufA + (buf ^ 1) * 256);

    // --- P2 ---
    {
      const int kb = tid & 31;
      f32x4 wa0 = w04[kb * 2], wa1 = w04[kb * 2 + 1];
      f32x4 wb0 = w04[64 + kb * 2], wb1 = w04[64 + kb * 2 + 1];
      f32x4 ba0 = b04[kb * 2], ba1 = b04[kb * 2 + 1];
      #pragma unroll
      for (int i = 0; i < 4; ++i) {
        int row = wave * 2 + 16 * i + (lane >> 5);
        float h0 = ocur[row * 3 + 1], h1 = ocur[row * 3 + 2];
        f32x4 va, vb;
        #pragma unroll
        for (int j = 0; j < 4; ++j) {
          va[j] = fmaxf(fmaf(h0, wa0[j], fmaf(h1, wb0[j], ba0[j])), 0.0f);
          vb[j] = fmaxf(fmaf(h0, wa1[j], fmaf(h1, wb1[j], ba1[j])), 0.0f);
        }
        u32x4 v;
        v[0] = cvt_pk_bf16(va[0], va[1]);
        v[1] = cvt_pk_bf16(va[2], va[3]);
        v[2] = cvt_pk_bf16(vb[0], vb[1]);
        v[3] = cvt_pk_bf16(vb[2], vb[3]);
        *(u32x4*)(smem + C_ACT1 + row * 512 + ((kb * 16) ^ SWZ(row))) = v;
      }
    }
    if (tid < 192) onxt[tid] = sob;
    { int c2 = c + 2 * stride; if (c2 < NCHUNK && tid < 192) sob = ob[c2 * 192 + tid]; }
    __syncthreads();                              // B2

    // --- P3 ---
    const bool evn = (l15 & 1) == 0;
    #pragma unroll 1
    for (int rtp = 0; rtp < 2; ++rtp) {
      f32x4 acc[2][2];
      #pragma unroll
      for (int h = 0; h < 2; ++h)
        #pragma unroll
        for (int ct = 0; ct < 2; ++ct) acc[h][ct] = (f32x4){0.f, 0.f, 0.f, 0.f};
      const int rA0 = rtp * 32 + l15, rA1 = rA0 + 16;
      #pragma unroll
      for (int ks = 0; ks < 8; ++ks) {
        const int cb = ks * 64 + 16 * l4;
        bf16x8 a0 = *(const bf16x8*)(smem + C_ACT1 + rA0 * 512 + (cb ^ SWZ(rA0)));
        bf16x8 a1 = *(const bf16x8*)(smem + C_ACT1 + rA1 * 512 + (cb ^ SWZ(rA1)));
        acc[0][0] = __builtin_amdgcn_mfma_f32_16x16x32_bf16(a0, bh[0][ks], acc[0][0], 0, 0, 0);
        acc[0][1] = __builtin_amdgcn_mfma_f32_16x16x32_bf16(a0, bh[1][ks], acc[0][1], 0, 0, 0);
        acc[1][0] = __builtin_amdgcn_mfma_f32_16x16x32_bf16(a1, bh[0][ks], acc[1][0], 0, 0, 0);
        acc[1][1] = __builtin_amdgcn_mfma_f32_16x16x32_bf16(a1, bh[1][ks], acc[1][1], 0, 0, 0);
      }
      #pragma unroll
      for (int ct = 0; ct < 2; ++ct) {
        const int colb = (colbase + ct * 16 + (l15 & ~1)) * 2;
        #pragma unroll
        for (int r = 0; r < 4; ++r) {
          float v0 = fmaxf(acc[0][ct][r] + b1lane[ct], 0.0f);
          float v1 = fmaxf(acc[1][ct][r] + b1lane[ct], 0.0f);
          float n0 = dppf<0xB1>(v0), n1 = dppf<0xB1>(v1);
          uint32_t w = cvt_pk_bf16(evn ? v0 : n1, evn ? n0 : v1);
          int rr = rtp * 32 + (evn ? 0 : 16) + 4 * l4 + r;
          *(uint32_t*)(smem + C_ACT2 + rr * 512 + (colb ^ SWZ(rr))) = w;
        }
      }
    }
    __syncthreads();                              // B3

    // --- P4: VALU head, waves 0-3, A-frag read pattern (rows = l15, 2-way-free) ---
    if (wave < 4) {
      const int rt = wave;
      const int row = rt * 16 + l15;
      const int sw = SWZ(row);
      float val = 0.0f;
      #pragma unroll
      for (int ks = 0; ks < 8; ++ks) {
        bf16x8 a = *(const bf16x8*)(smem + C_ACT2 + row * 512 + ((ks * 64 + 16 * l4) ^ sw));
        f32x4 wA = w24[ks * 8 + 2 * l4], wB = w24[ks * 8 + 2 * l4 + 1];
        #pragma unroll
        for (int j = 0; j < 4; ++j) {
          val = fmaf(bf2f(a[j]), wA[j], val);
          val = fmaf(bf2f(a[4 + j]), wB[j], val);
        }
      }
      val += __shfl_xor(val, 16);                 // reduce over l4 (k-slices)
      val += __shfl_xor(val, 32);
      if (l4 == 0) {
        float o0 = ob[(row0 + row) * 3];
        if ((int)o0 == 0) {
          int g = graph_ids[c * 4 + rt];
          atomicAdd(&out[OUT_VP + g * 16 + l15], (val + cb2v) * (1.0f / 50000.0f));
        }
      }
    }
  }
}

extern "C" void kernel_launch(void* const* d_in, const int* in_sizes, int n_in,
                              void* d_out, int out_size, void* d_ws, size_t ws_size,
                              hipStream_t stream) {
  const float* ob     = (const float*)d_in[0];
  const int*   action = (const int*)d_in[1];
  const int*   gids   = (const int*)d_in[2];
  const float* aW0 = (const float*)d_in[3],  *ab0 = (const float*)d_in[4];
  const float* aW1 = (const float*)d_in[5],  *ab1 = (const float*)d_in[6];
  const float* aW2 = (const float*)d_in[7],  *ab2 = (const float*)d_in[8];
  const float* cW0 = (const float*)d_in[9],  *cb0 = (const float*)d_in[10];
  const float* cW1 = (const float*)d_in[11], *cb1 = (const float*)d_in[12];
  const float* cW2 = (const float*)d_in[13], *cb2 = (const float*)d_in[14];
  float* out = (float*)d_out;
  float* wsf = (float*)d_ws;

  zero_kernel<<<2, 512, 0, stream>>>(out, wsf);
  ac_actor<<<512, 512, A_SZ, stream>>>(ob, action, aW0, ab0, aW1, ab1, aW2, ab2, out, wsf);
  ac_critic<<<512, 512, C_SZ, stream>>>(ob, gids, cW0, cb0, cW1, cb1, cW2, cb2, out);
  final_kernel<<<1, 64, 0, stream>>>(out, wsf);
}